// Round 15
// baseline (116.265 us; speedup 1.0000x reference)
//
#include <hip/hip_runtime.h>
#include <math.h>

// ShadowMapping forward: hard + soft shadow maps.
// R15: epoch-batched MLP — 4 tasks/thread (2 half-row pixels x 2 lights),
//      phase-separated: [A] coalesced depth/mask x2 -> [B] geometry x4 ->
//      [C] ALL scattered taps issued back-to-back (one vmcnt drain) ->
//      [D] poly + stores. Halves memory round-trips per task, ~4x
//      outstanding scattered loads per wave at equal wave count (R12's
//      2-light variant failed by halving waves; this holds grid shape).
//      Numerics byte-identical per task to R13/R14 (mask gating, w1<0.0056
//      1-tap mode, plus-stencil, poly-sin, geometry chain).

#define RESN 512
#define NL 16
#define NPIX (RESN*RESN)

__global__ void setup_kernel(const float* __restrict__ als,
                             float* __restrict__ lp) {
  #pragma clang fp contract(off)
  int l = (int)threadIdx.x;
  if (l >= NL) return;
  float xd = als[l*7+0], yd = als[l*7+1], zd = als[l*7+2], sg = als[l*7+3];
  float cosp = sqrtf(xd*xd + zd*zd);
  float cost = zd / cosp;
  float sint = xd / cosp;
  float* o = lp + l*16;
  o[0] = cost;               // e00
  o[1] = -sint;              // e02
  o[2] = (-sint)*yd;         // e10
  o[3] = cosp;               // e11
  o[4] = (-cost)*yd;         // e12
  o[5] = cosp*sint;          // e20
  o[6] = yd;                 // e21
  o[7] = cosp*cost;          // e22
  // radius-1 Gaussian, normalized over the full 21-tap sum (validated R6)
  float sig = ((2.0f*(6.0f*sg + 1.0f)) - 1.0f) / 6.0f;
  float ivs = 1.0f/(sig*sig);
  float e1  = __builtin_amdgcn_exp2f(-0.72134752044448170368f*ivs);
  float e1sq = e1*e1;
  float e2  = e1sq*e1sq;
  float kinv = 1.0f/(1.0f + 2.0f*e1 + 2.0f*e2);
  float w1n = e1*kinv;
  o[8] = kinv;               // w0
  o[9] = w1n;                // w1
  o[10] = (w1n >= 0.0056f) ? 1.0f : 0.0f;      // 5-tap mode flag
  o[11] = kinv*kinv;         // w0^2 (1-tap path)
  o[12] = o[13] = o[14] = o[15] = 0.0f;
}

__global__ __launch_bounds__(256) void fused_kernel(
    const float* __restrict__ depth,
    const float* __restrict__ mask,
    const float* __restrict__ z_map,
    const float* __restrict__ lp,
    float* __restrict__ out,
    float TANHF, float OZF, float OWF)
{
  #pragma clang fp contract(off)
  const float OFFS = -0.0642233295781f;
  const float CLB  = 0.4458709375254f;
  const float TWO_OVER_PI = 0.63661977236758134308f;
  // 4096 blocks: id&7 = light pair (l, l+8) — XCD affinity; id>>3 = row.
  // Thread handles columns c and c+256 of that row (2 pixels x 2 lights).
  const int id = (int)blockIdx.x;
  const int l0 = id & 7;
  const int r  = id >> 3;
  const int tid = (int)threadIdx.x;
  const float m1r = 2.0f * ((float)r / 512.0f + 0.0009765625f) - 1.0f;

  // per-light uniforms (block-uniform scalar loads; setup did the VALU math)
  float e00[2], e02[2], e10[2], e11[2], e12[2], e20[2], e21[2], e22[2];
  float w0c[2], w1c[2], w0sq[2];
  bool ftap[2];
  #pragma unroll
  for (int k = 0; k < 2; ++k) {
    const float* P = lp + (l0 + (k<<3))*16;
    e00[k]=P[0]; e02[k]=P[1]; e10[k]=P[2]; e11[k]=P[3]; e12[k]=P[4];
    e20[k]=P[5]; e21[k]=P[6]; e22[k]=P[7];
    w0c[k]=P[8]; w1c[k]=P[9]; ftap[k]=P[10]!=0.0f; w0sq[k]=P[11];
  }

  // ---- phase A: coalesced input loads (both pixels issued back-to-back) --
  int C[2];  C[0] = tid;  C[1] = tid + 256;
  int Pp[2]; Pp[0] = (r<<9) + C[0]; Pp[1] = (r<<9) + C[1];
  float dzv[2], mkv[2];
  dzv[0] = depth[Pp[0]]; dzv[1] = depth[Pp[1]];
  mkv[0] = mask[Pp[0]];  mkv[1] = mask[Pp[1]];

  // ---- phase B: geometry x4 (VALU only; validated fmuladd chain) ---------
  int U[2][2], V[2][2];
  float DD[2][2], DPO[2][2];
  bool live[2];
  #pragma unroll
  for (int i = 0; i < 2; ++i) {
    live[i] = (mkv[i] != 0.0f);
    float dz = dzv[i];
    float m1c = 2.0f * ((float)C[i] / 512.0f + 0.0009765625f) - 1.0f;
    float tT = dz * TANHF;
    float qx = tT * m1c;
    float qy = tT * m1r;
    float qz = 2.7f - dz;
    #pragma unroll
    for (int k = 0; k < 2; ++k) {
      float X1 = fmaf(qz, e02[k], qx * e00[k]);
      float Y1 = fmaf(qz, e12[k], fmaf(qy, e11[k], qx * e10[k]));
      float T2 = fmaf(qz, e22[k], fmaf(qy, e21[k], qx * e20[k]));
      float Z1 = T2 + (-2.7f);
      float ZZ = (Z1 * OZF) + OWF;
      float uf = (X1 + 1.0f) * 256.0f;
      float vf = (Y1 + 1.0f) * 256.0f;
      int u = (int)uf; u = u < 0 ? 0 : (u > 511 ? 511 : u);
      int v = (int)vf; v = v < 0 ? 0 : (v > 511 ? 511 : v);
      float dd = 0.5f * (1.0f + ZZ);
      dd = fminf(fmaxf(dd, 0.0f), 1.0f);
      U[i][k] = u; V[i][k] = v; DD[i][k] = dd; DPO[i][k] = dd + OFFS;
    }
  }

  // ---- phase C: issue ALL scattered taps before any use ------------------
  float ZG[2][2], ZT[2][2], ZL[2][2], ZR[2][2], ZB[2][2];
  #pragma unroll
  for (int i = 0; i < 2; ++i) {
    if (live[i]) {
      #pragma unroll
      for (int k = 0; k < 2; ++k) {
        const int base = (l0 + (k<<3)) << 18;
        int u = U[i][k], v = V[i][k];
        const float* zrC = z_map + base + (v << 9);
        ZG[i][k] = zrC[u];
        if (ftap[k]) {
          int u0 = u > 0 ? u - 1 : 0;
          int u2 = u < 511 ? u + 1 : 511;
          int v0 = v > 0 ? v - 1 : 0;
          int v2 = v < 511 ? v + 1 : 511;
          ZT[i][k] = z_map[base + (v0 << 9) + u];
          ZL[i][k] = zrC[u0];
          ZR[i][k] = zrC[u2];
          ZB[i][k] = z_map[base + (v2 << 9) + u];
        }
      }
    }
  }

  // ---- phase D: poly + outputs -------------------------------------------
  #pragma unroll
  for (int i = 0; i < 2; ++i) {
    #pragma unroll
    for (int k = 0; k < 2; ++k) {
      const int base = (l0 + (k<<3)) << 18;
      float hard_out = 0.0f, soft_out = 0.0f;
      if (live[i]) {
        float dpo = DPO[i][k];
        // f = sum_{m odd<=7} (1/m) sin(m*pi*(z-dpo)) = s*P(s^2)
        auto fval = [&](float z) {
          float s = __builtin_amdgcn_sinf(0.5f * (z - dpo));   // revolutions
          float t = s * s;
          return s * fmaf(t, fmaf(t, fmaf(t, -9.142857142857142f, 19.2f),
                                  -13.333333333333334f), 4.0f);
        };
        float zg = ZG[i][k];
        float q;
        if (ftap[k]) {
          int u = U[i][k], v = V[i][k];
          float w1 = w1c[k];
          float wuL = (u > 0)   ? w1 : 0.0f;
          float wuR = (u < 511) ? w1 : 0.0f;
          float wvT = (v > 0)   ? w1 : 0.0f;
          float wvB = (v < 511) ? w1 : 0.0f;
          float qs = w0c[k] * fval(zg);
          qs = fmaf(wvT, fval(ZT[i][k]), qs);
          qs = fmaf(wvB, fval(ZB[i][k]), qs);
          qs = fmaf(wuL, fval(ZL[i][k]), qs);
          qs = fmaf(wuR, fval(ZR[i][k]), qs);
          q = TWO_OVER_PI * (w0c[k] * qs);
        } else {
          // 1-tap mode: side weights < 5.6e-3 dropped (validated R13)
          q = TWO_OVER_PI * (w0sq[k] * fval(zg));
        }
        float diff = fmaxf(DD[i][k] - zg, 0.0f);
        hard_out = mkv[i] * ((diff > 0.008f) ? 0.0f : 1.0f);
        float qc = fminf(fmaxf(q, -CLB), CLB) / CLB;
        float sf = 0.5f * (qc + 1.0f);
        soft_out = mkv[i] * fminf(fmaxf(sf, 0.0f), 1.0f);
      }
      out[base + Pp[i]] = hard_out;
      out[(NL*NPIX) + base + Pp[i]] = soft_out;
    }
  }
}

extern "C" void kernel_launch(void* const* d_in, const int* in_sizes, int n_in,
                              void* d_out, int out_size, void* d_ws, size_t ws_size,
                              hipStream_t stream) {
  (void)in_sizes; (void)n_in; (void)out_size; (void)ws_size;
  const float* depth = (const float*)d_in[0];
  const float* als   = (const float*)d_in[1];
  const float* mask  = (const float*)d_in[2];
  const float* z_map = (const float*)d_in[3];
  float* out = (float*)d_out;
  float* lp = (float*)d_ws;                       // 16 lights x 16 floats = 1KB
  // constants in double, replicating numpy, then rounded to f32
  double TANH = tan(2.0*atan(0.5*36.0/50.0)/2.0);
  double NEARc = 2.7 - sqrt(2.0)*2.7*TANH;
  double FARc  = 2.7 + sqrt(2.0)*2.7*TANH;
  float ozf = (float)(-2.0/(FARc-NEARc));
  float owf = (float)((-(FARc+NEARc))/(FARc-NEARc));
  float tanhf_ = (float)TANH;

  setup_kernel<<<1, 64, 0, stream>>>(als, lp);
  // 4096 blocks x 256 thr: 2 half-row pixels x 2 lights per thread
  fused_kernel<<<(NL/2)*RESN, 256, 0, stream>>>(depth, mask, z_map, lp,
                                                out, tanhf_, ozf, owf);
}